// Round 5
// baseline (114.284 us; speedup 1.0000x reference)
//
#include <hip/hip_runtime.h>
#include <hip/hip_bf16.h>

// RegionCodecDict: out[b,t,idx[r][n]] = sum_m spikes[b,t,idx[r][m]] * M[r][m][n] + c[r][n]
// where M[r] = W_enc[r] @ W_dec[r]  (128x128), c[r] = b_enc[r] @ W_dec[r] + b_dec[r]
// (the reference is purely linear between the two einsums, so they collapse).
//
// ws layout (~2.4 MB):
//   pos    : int[1024]               @ 0        inverse permutation
//   c      : float[8*128]            @ 4096
//   MT     : ushort(bf16)[8*128*128] @ 8192     MT[r][n][k] = M[r][k][n]
//   part   : float[32*16384]         @ 270336   per-(r,dc) 128x128 f32 GEMM partials
//   part_c : float[32*8*128]         @ 2367488  per-(r,dc,dlb) c partials

typedef __attribute__((ext_vector_type(8))) short bf16x8;
typedef __attribute__((ext_vector_type(4))) float f32x4;
typedef __attribute__((ext_vector_type(4))) short s16x4;

#define NREG 8
#define NRD  128
#define DD   512
#define NN   1024
#define ROWS 16

static __device__ __forceinline__ unsigned short f2bf(float x) {
  union { float f; unsigned u; } v; v.f = x;
  unsigned r = v.u + 0x7fffu + ((v.u >> 16) & 1u);   // RNE
  return (unsigned short)(r >> 16);
}
// header conversion (hardware cvt where available); bit-identical RNE
static __device__ __forceinline__ unsigned short f2bf_hw(float x) {
  union { __hip_bfloat16 h; unsigned short u; } c;
  c.h = __float2bfloat16(x);
  return c.u;
}

// ---------- prep1: 32 GEMM-partial blocks (r x d-chunk) + 1 pos block ----------
__global__ __launch_bounds__(256) void prep1_kernel(
    const float* __restrict__ W_enc, const float* __restrict__ b_enc,
    const float* __restrict__ W_dec, const int* __restrict__ idx,
    int* __restrict__ pos_ws, float* __restrict__ part,
    float* __restrict__ part_c)
{
  __shared__ unsigned short As[128 * 128];   // As[n][d^sw(n)]  (Wd^T slice)
  __shared__ unsigned short Bs[128 * 128];   // Bs[k][d^sw(k)]  (We slice)
  int blk = blockIdx.x, t = threadIdx.x;

  if (blk < 32) {
    int r = blk >> 2, dc = blk & 3, d0 = dc * 128;
    const float* We = W_enc + (size_t)r * NRD * DD;
    const float* Wd = W_dec + (size_t)r * DD * NRD;
    const float* be = b_enc + (size_t)r * DD;

    // stage As: transpose-scatter Wd[d0+dl][n] -> As[n][dl^sw]; fuse c partials
    int n4 = (t & 31) * 4, dlb = t >> 5;     // dlb in 0..7
    float c0 = 0.f, c1 = 0.f, c2 = 0.f, c3 = 0.f;
    #pragma unroll
    for (int p = 0; p < 16; ++p) {
      int dl = dlb + p * 8;
      float4 v = *(const float4*)&Wd[(size_t)(d0 + dl) * NRD + n4];
      float bev = be[d0 + dl];
      As[(n4 + 0) * 128 + (dl ^ (((n4 + 0) & 7) << 3))] = f2bf(v.x);
      As[(n4 + 1) * 128 + (dl ^ (((n4 + 1) & 7) << 3))] = f2bf(v.y);
      As[(n4 + 2) * 128 + (dl ^ (((n4 + 2) & 7) << 3))] = f2bf(v.z);
      As[(n4 + 3) * 128 + (dl ^ (((n4 + 3) & 7) << 3))] = f2bf(v.w);
      c0 += v.x * bev; c1 += v.y * bev; c2 += v.z * bev; c3 += v.w * bev;
    }
    {
      float4 cv; cv.x = c0; cv.y = c1; cv.z = c2; cv.w = c3;
      *(float4*)&part_c[((size_t)(r * 4 + dc) * 8 + dlb) * 128 + n4] = cv;
    }
    // stage Bs: straight copy We[k][d0..d0+128]
    #pragma unroll
    for (int i = 0; i < 8; ++i) {
      int cid = t + i * 256;
      int k = cid >> 4, dq = (cid & 15) * 8;
      const float* src = &We[(size_t)k * DD + d0 + dq];
      float4 u = *(const float4*)src;
      float4 u2 = *(const float4*)(src + 4);
      bf16x8 pk;
      pk[0] = (short)f2bf(u.x);  pk[1] = (short)f2bf(u.y);
      pk[2] = (short)f2bf(u.z);  pk[3] = (short)f2bf(u.w);
      pk[4] = (short)f2bf(u2.x); pk[5] = (short)f2bf(u2.y);
      pk[6] = (short)f2bf(u2.z); pk[7] = (short)f2bf(u2.w);
      *(bf16x8*)&Bs[k * 128 + (dq ^ ((k & 7) << 3))] = pk;
    }
    __syncthreads();

    int lane = t & 63, w = t >> 6;
    int arow = lane & 15, ag = lane >> 4;
    f32x4 acc[8][2];
    #pragma unroll
    for (int i = 0; i < 8; ++i) {
      acc[i][0] = (f32x4){0.f, 0.f, 0.f, 0.f};
      acc[i][1] = (f32x4){0.f, 0.f, 0.f, 0.f};
    }
    #pragma unroll
    for (int nt = 0; nt < 8; ++nt) {
      int nl = nt * 16 + arow, asw = (nl & 7) << 3;
      bf16x8 a[4];
      #pragma unroll
      for (int ks = 0; ks < 4; ++ks)
        a[ks] = *(const bf16x8*)&As[nl * 128 + ((ks * 32 + ag * 8) ^ asw)];
      #pragma unroll
      for (int kt = 0; kt < 2; ++kt) {
        int kk = w * 32 + kt * 16 + arow, bsw = (kk & 7) << 3;
        #pragma unroll
        for (int ks = 0; ks < 4; ++ks) {
          bf16x8 b = *(const bf16x8*)&Bs[kk * 128 + ((ks * 32 + ag * 8) ^ bsw)];
          acc[nt][kt] = __builtin_amdgcn_mfma_f32_16x16x32_bf16(a[ks], b, acc[nt][kt], 0, 0, 0);
        }
      }
    }
    float* dst = part + (size_t)(r * 4 + dc) * 16384;
    #pragma unroll
    for (int nt = 0; nt < 8; ++nt)
      #pragma unroll
      for (int kt = 0; kt < 2; ++kt)
        #pragma unroll
        for (int v = 0; v < 4; ++v)
          dst[(nt * 16 + ag * 4 + v) * 128 + (w * 32 + kt * 16 + arow)] = acc[nt][kt][v];
  } else {
    // pos block
    #pragma unroll
    for (int i = 0; i < 4; ++i) {
      int q = t * 4 + i;
      pos_ws[idx[q]] = q;
    }
  }
}

// ---------- prep2: reduce partials -> MT (bf16) and c (f32) ----------
__global__ __launch_bounds__(256) void prep2_kernel(
    const float* __restrict__ part, const float* __restrict__ part_c,
    const float* __restrict__ b_dec, unsigned short* __restrict__ MT_ws,
    float* __restrict__ c_ws)
{
  int blk = blockIdx.x, t = threadIdx.x;
  if (blk < 128) {
    int e0 = (blk * 256 + t) * 4;
    int r = e0 >> 14, off = e0 & 16383;
    const float* p = part + (size_t)r * 4 * 16384 + off;
    float4 s0 = *(const float4*)&p[0];
    float4 s1 = *(const float4*)&p[16384];
    float4 s2 = *(const float4*)&p[32768];
    float4 s3 = *(const float4*)&p[49152];
    s16x4 o;
    o.x = (short)f2bf(s0.x + s1.x + s2.x + s3.x);
    o.y = (short)f2bf(s0.y + s1.y + s2.y + s3.y);
    o.z = (short)f2bf(s0.z + s1.z + s2.z + s3.z);
    o.w = (short)f2bf(s0.w + s1.w + s2.w + s3.w);
    *(s16x4*)&MT_ws[e0] = o;
  } else if (blk < 132) {
    int e = (blk - 128) * 256 + t;
    int n = e & 127;
    int r = e >> 7;
    float s = b_dec[e];
    #pragma unroll
    for (int dc = 0; dc < 4; ++dc)
      #pragma unroll
      for (int g = 0; g < 8; ++g)
        s += part_c[((size_t)(r * 4 + dc) * 8 + g) * 128 + n];
    c_ws[e] = s;
  }
}

// ---------- main codec: stage -> ONE barrier -> MFMA + direct scattered f32 stores ----------
// Output permutation baked into the store address: lane (w,arow) region r writes
// column idx[r][w*16+arow] directly. Each block covers all 1024 cols of its 16
// rows within one phase, so scattered dword stores assemble into full lines in L2.
__global__ __launch_bounds__(512) void codec_kernel(
    const float* __restrict__ spikes, const int* __restrict__ pos_ws,
    const float* __restrict__ c_ws, const unsigned short* __restrict__ MT_ws,
    const int* __restrict__ idx, float* __restrict__ out)
{
  // Xs[row][q]: bf16 at elem index row*1024 + (q ^ ((row&7)<<3))
  __shared__ unsigned short Xs[ROWS * NN];   // 32KB input (region-permuted)
  int t = threadIdx.x;
  int w = t >> 6, lane = t & 63;             // 8 waves
  int arow = lane & 15, ag = lane >> 4;
  int n0 = w * 16 + arow;                    // wave w owns region-cols [16w, 16w+16)
  size_t row0 = (size_t)blockIdx.x * ROWS;

  // register-cached permutation, bias, output columns
  int4 p4c[4];
  #pragma unroll
  for (int ch = 0; ch < 4; ++ch)
    p4c[ch] = *(const int4*)&pos_ws[ch * 256 + lane * 4];
  float cv[NREG];
  int col[NREG];
  #pragma unroll
  for (int r = 0; r < NREG; ++r) {
    cv[r]  = c_ws[r * 128 + n0];
    col[r] = idx[r * 128 + n0];
  }

  // ---- stage: coalesced float4 reads (2 rows per wave), bf16 scatter into permuted LDS
  #pragma unroll
  for (int ch = 0; ch < 4; ++ch) {
    int j = ch * 256 + lane * 4;
    int4 p4 = p4c[ch];
    #pragma unroll
    for (int rl = 0; rl < 2; ++rl) {
      int row = w * 2 + rl;
      float4 v = *(const float4*)&spikes[(row0 + row) * NN + j];
      int base = row * NN, sw = (row & 7) << 3;
      Xs[base + (p4.x ^ sw)] = f2bf_hw(v.x);
      Xs[base + (p4.y ^ sw)] = f2bf_hw(v.y);
      Xs[base + (p4.z ^ sw)] = f2bf_hw(v.z);
      Xs[base + (p4.w ^ sw)] = f2bf_hw(v.w);
    }
  }
  __syncthreads();

  // ---- per region: A from LDS (swizzled), B from L2-resident MT, store f32 direct
  int asw = (arow & 7) << 3;
  #pragma unroll
  for (int r = 0; r < NREG; ++r) {
    bf16x8 a[4];
    #pragma unroll
    for (int kt = 0; kt < 4; ++kt)
      a[kt] = *(const bf16x8*)&Xs[arow * NN + ((r * 128 + kt * 32 + ag * 8) ^ asw)];
    const bf16x8* b = (const bf16x8*)(MT_ws + (size_t)(r * 128 + n0) * 128 + ag * 8);
    f32x4 acc = {0.f, 0.f, 0.f, 0.f};
    #pragma unroll
    for (int kt = 0; kt < 4; ++kt)          // b[kt*4]: +32 bf16 = next K-subtile
      acc = __builtin_amdgcn_mfma_f32_16x16x32_bf16(a[kt], b[kt * 4], acc, 0, 0, 0);
    float* op = out + (row0 + ag * 4) * NN + col[r];
    #pragma unroll
    for (int v = 0; v < 4; ++v)             // D[i][j]: i = 4*(lane/16)+v, j = lane%16
      op[(size_t)v * NN] = acc[v] + cv[r];
  }
}

extern "C" void kernel_launch(void* const* d_in, const int* in_sizes, int n_in,
                              void* d_out, int out_size, void* d_ws, size_t ws_size,
                              hipStream_t stream) {
  const float* spikes = (const float*)d_in[0];
  const float* W_enc  = (const float*)d_in[1];
  const float* b_enc  = (const float*)d_in[2];
  const float* W_dec  = (const float*)d_in[3];
  const float* b_dec  = (const float*)d_in[4];
  const int*   idx    = (const int*)d_in[5];
  float* out = (float*)d_out;

  char* ws = (char*)d_ws;
  int*            pos_ws  = (int*)ws;
  float*          c_ws    = (float*)(ws + 4096);
  unsigned short* MT_ws   = (unsigned short*)(ws + 8192);
  float*          part    = (float*)(ws + 270336);
  float*          part_c  = (float*)(ws + 2367488);

  prep1_kernel<<<33, 256, 0, stream>>>(W_enc, b_enc, W_dec, idx,
                                       pos_ws, part, part_c);
  prep2_kernel<<<132, 256, 0, stream>>>(part, part_c, b_dec, MT_ws, c_ws);
  codec_kernel<<<8192 / ROWS, 512, 0, stream>>>(spikes, pos_ws, c_ws, MT_ws, idx, out);
}

// Round 6
// 39.723 us; speedup vs baseline: 2.8770x; 2.8770x over previous
//
#include <hip/hip_runtime.h>
#include <hip/hip_bf16.h>

// RegionCodecDict: out[b,t,idx[r][n]] = sum_m spikes[b,t,idx[r][m]] * M[r][m][n] + c[r][n]
// where M[r] = W_enc[r] @ W_dec[r]  (128x128), c[r] = b_enc[r] @ W_dec[r] + b_dec[r]
// (the reference is purely linear between the two einsums, so they collapse).
//
// ws layout (~2.4 MB):
//   pos    : int[1024]               @ 0        inverse permutation
//   c      : float[8*128]            @ 4096
//   MT     : ushort(bf16)[8*128*128] @ 8192     MT[r][n][k] = M[r][k][n]
//   part   : float[32*16384]         @ 270336   per-(r,dc) 128x128 f32 GEMM partials
//   part_c : float[32*8*128]         @ 2367488  per-(r,dc,dlb) c partials

typedef __attribute__((ext_vector_type(8))) short bf16x8;
typedef __attribute__((ext_vector_type(4))) float f32x4;
typedef __attribute__((ext_vector_type(4))) short s16x4;

#define NREG 8
#define NRD  128
#define DD   512
#define NN   1024
#define ROWS 16           // rows per subtile
#define SUBT 2            // subtiles per block (pipelined)

static __device__ __forceinline__ unsigned short f2bf(float x) {
  union { float f; unsigned u; } v; v.f = x;
  unsigned r = v.u + 0x7fffu + ((v.u >> 16) & 1u);   // RNE
  return (unsigned short)(r >> 16);
}
static __device__ __forceinline__ unsigned short f2bf_hw(float x) {
  union { __hip_bfloat16 h; unsigned short u; } c;
  c.h = __float2bfloat16(x);
  return c.u;
}
static __device__ __forceinline__ float bf2f(unsigned short b) {
  union { unsigned u; float f; } v; v.u = ((unsigned)b) << 16;
  return v.f;
}

// ---------- prep1: 32 GEMM-partial blocks (r x d-chunk) + 1 pos block ----------
__global__ __launch_bounds__(256) void prep1_kernel(
    const float* __restrict__ W_enc, const float* __restrict__ b_enc,
    const float* __restrict__ W_dec, const int* __restrict__ idx,
    int* __restrict__ pos_ws, float* __restrict__ part,
    float* __restrict__ part_c)
{
  __shared__ unsigned short As[128 * 128];   // As[n][d^sw(n)]  (Wd^T slice)
  __shared__ unsigned short Bs[128 * 128];   // Bs[k][d^sw(k)]  (We slice)
  int blk = blockIdx.x, t = threadIdx.x;

  if (blk < 32) {
    int r = blk >> 2, dc = blk & 3, d0 = dc * 128;
    const float* We = W_enc + (size_t)r * NRD * DD;
    const float* Wd = W_dec + (size_t)r * DD * NRD;
    const float* be = b_enc + (size_t)r * DD;

    // stage As: transpose-scatter Wd[d0+dl][n] -> As[n][dl^sw]; fuse c partials
    int n4 = (t & 31) * 4, dlb = t >> 5;     // dlb in 0..7
    float c0 = 0.f, c1 = 0.f, c2 = 0.f, c3 = 0.f;
    #pragma unroll
    for (int p = 0; p < 16; ++p) {
      int dl = dlb + p * 8;
      float4 v = *(const float4*)&Wd[(size_t)(d0 + dl) * NRD + n4];
      float bev = be[d0 + dl];
      As[(n4 + 0) * 128 + (dl ^ (((n4 + 0) & 7) << 3))] = f2bf(v.x);
      As[(n4 + 1) * 128 + (dl ^ (((n4 + 1) & 7) << 3))] = f2bf(v.y);
      As[(n4 + 2) * 128 + (dl ^ (((n4 + 2) & 7) << 3))] = f2bf(v.z);
      As[(n4 + 3) * 128 + (dl ^ (((n4 + 3) & 7) << 3))] = f2bf(v.w);
      c0 += v.x * bev; c1 += v.y * bev; c2 += v.z * bev; c3 += v.w * bev;
    }
    {
      float4 cv; cv.x = c0; cv.y = c1; cv.z = c2; cv.w = c3;
      *(float4*)&part_c[((size_t)(r * 4 + dc) * 8 + dlb) * 128 + n4] = cv;
    }
    // stage Bs: straight copy We[k][d0..d0+128]
    #pragma unroll
    for (int i = 0; i < 8; ++i) {
      int cid = t + i * 256;
      int k = cid >> 4, dq = (cid & 15) * 8;
      const float* src = &We[(size_t)k * DD + d0 + dq];
      float4 u = *(const float4*)src;
      float4 u2 = *(const float4*)(src + 4);
      bf16x8 pk;
      pk[0] = (short)f2bf(u.x);  pk[1] = (short)f2bf(u.y);
      pk[2] = (short)f2bf(u.z);  pk[3] = (short)f2bf(u.w);
      pk[4] = (short)f2bf(u2.x); pk[5] = (short)f2bf(u2.y);
      pk[6] = (short)f2bf(u2.z); pk[7] = (short)f2bf(u2.w);
      *(bf16x8*)&Bs[k * 128 + (dq ^ ((k & 7) << 3))] = pk;
    }
    __syncthreads();

    int lane = t & 63, w = t >> 6;
    int arow = lane & 15, ag = lane >> 4;
    f32x4 acc[8][2];
    #pragma unroll
    for (int i = 0; i < 8; ++i) {
      acc[i][0] = (f32x4){0.f, 0.f, 0.f, 0.f};
      acc[i][1] = (f32x4){0.f, 0.f, 0.f, 0.f};
    }
    #pragma unroll
    for (int nt = 0; nt < 8; ++nt) {
      int nl = nt * 16 + arow, asw = (nl & 7) << 3;
      bf16x8 a[4];
      #pragma unroll
      for (int ks = 0; ks < 4; ++ks)
        a[ks] = *(const bf16x8*)&As[nl * 128 + ((ks * 32 + ag * 8) ^ asw)];
      #pragma unroll
      for (int kt = 0; kt < 2; ++kt) {
        int kk = w * 32 + kt * 16 + arow, bsw = (kk & 7) << 3;
        #pragma unroll
        for (int ks = 0; ks < 4; ++ks) {
          bf16x8 b = *(const bf16x8*)&Bs[kk * 128 + ((ks * 32 + ag * 8) ^ bsw)];
          acc[nt][kt] = __builtin_amdgcn_mfma_f32_16x16x32_bf16(a[ks], b, acc[nt][kt], 0, 0, 0);
        }
      }
    }
    float* dst = part + (size_t)(r * 4 + dc) * 16384;
    #pragma unroll
    for (int nt = 0; nt < 8; ++nt)
      #pragma unroll
      for (int kt = 0; kt < 2; ++kt)
        #pragma unroll
        for (int v = 0; v < 4; ++v)
          dst[(nt * 16 + ag * 4 + v) * 128 + (w * 32 + kt * 16 + arow)] = acc[nt][kt][v];
  } else {
    // pos block
    #pragma unroll
    for (int i = 0; i < 4; ++i) {
      int q = t * 4 + i;
      pos_ws[idx[q]] = q;
    }
  }
}

// ---------- prep2: reduce partials -> MT (bf16) and c (f32) ----------
__global__ __launch_bounds__(256) void prep2_kernel(
    const float* __restrict__ part, const float* __restrict__ part_c,
    const float* __restrict__ b_dec, unsigned short* __restrict__ MT_ws,
    float* __restrict__ c_ws)
{
  int blk = blockIdx.x, t = threadIdx.x;
  if (blk < 128) {
    int e0 = (blk * 256 + t) * 4;
    int r = e0 >> 14, off = e0 & 16383;
    const float* p = part + (size_t)r * 4 * 16384 + off;
    float4 s0 = *(const float4*)&p[0];
    float4 s1 = *(const float4*)&p[16384];
    float4 s2 = *(const float4*)&p[32768];
    float4 s3 = *(const float4*)&p[49152];
    s16x4 o;
    o.x = (short)f2bf(s0.x + s1.x + s2.x + s3.x);
    o.y = (short)f2bf(s0.y + s1.y + s2.y + s3.y);
    o.z = (short)f2bf(s0.z + s1.z + s2.z + s3.z);
    o.w = (short)f2bf(s0.w + s1.w + s2.w + s3.w);
    *(s16x4*)&MT_ws[e0] = o;
  } else if (blk < 132) {
    int e = (blk - 128) * 256 + t;
    int n = e & 127;
    int r = e >> 7;
    float s = b_dec[e];
    #pragma unroll
    for (int dc = 0; dc < 4; ++dc)
      #pragma unroll
      for (int g = 0; g < 8; ++g)
        s += part_c[((size_t)(r * 4 + dc) * 8 + g) * 128 + n];
    c_ws[e] = s;
  }
}

// ---------- main codec: 2-subtile pipelined block ----------
// Block = 32 rows as two 16-row subtiles, double-buffered Xs, shared Ys.
//   stage T0 | B | prefetch T1 -> regs, compute T0 -> Ys, scatter T1 | B |
//   compute T1 -> acc regs  ||  gather+store T0 | B | acc -> Ys | B | gather+store T1
__global__ __launch_bounds__(512) void codec_kernel(
    const float* __restrict__ spikes, const int* __restrict__ pos_ws,
    const float* __restrict__ c_ws, const unsigned short* __restrict__ MT_ws,
    float* __restrict__ out)
{
  // Xs/Ys[row][q]: bf16 at elem index row*1024 + (q ^ ((row&7)<<3))
  __shared__ unsigned short Xs[SUBT][ROWS * NN];   // 2 x 32KB
  __shared__ unsigned short Ys[ROWS * NN];         // 32KB
  int t = threadIdx.x;
  int w = t >> 6, lane = t & 63;             // 8 waves
  int arow = lane & 15, ag = lane >> 4;
  int n0 = w * 16 + arow;                    // wave w owns region-cols [16w, 16w+16)
  int asw = (arow & 7) << 3;
  size_t row0 = (size_t)blockIdx.x * (ROWS * SUBT);

  // register-cached permutation and bias
  int4 p4c[4];
  #pragma unroll
  for (int ch = 0; ch < 4; ++ch)
    p4c[ch] = *(const int4*)&pos_ws[ch * 256 + lane * 4];
  float cv[NREG];
  #pragma unroll
  for (int r = 0; r < NREG; ++r)
    cv[r] = c_ws[r * 128 + n0];

  // ---- stage T0
  #pragma unroll
  for (int ch = 0; ch < 4; ++ch) {
    int j = ch * 256 + lane * 4;
    int4 p4 = p4c[ch];
    #pragma unroll
    for (int rl = 0; rl < 2; ++rl) {
      int row = w * 2 + rl;
      float4 v = *(const float4*)&spikes[(row0 + row) * NN + j];
      int base = row * NN, sw = (row & 7) << 3;
      Xs[0][base + (p4.x ^ sw)] = f2bf_hw(v.x);
      Xs[0][base + (p4.y ^ sw)] = f2bf_hw(v.y);
      Xs[0][base + (p4.z ^ sw)] = f2bf_hw(v.z);
      Xs[0][base + (p4.w ^ sw)] = f2bf_hw(v.w);
    }
  }
  __syncthreads();                                           // (1)

  // ---- prefetch T1 global rows into regs (latency hides under compute T0)
  float4 pv[4][2];
  #pragma unroll
  for (int ch = 0; ch < 4; ++ch)
    #pragma unroll
    for (int rl = 0; rl < 2; ++rl)
      pv[ch][rl] = *(const float4*)&spikes[(row0 + ROWS + w * 2 + rl) * NN + ch * 256 + lane * 4];

  // ---- compute T0 -> Ys
  #pragma unroll
  for (int r = 0; r < NREG; ++r) {
    bf16x8 a[4];
    #pragma unroll
    for (int kt = 0; kt < 4; ++kt)
      a[kt] = *(const bf16x8*)&Xs[0][arow * NN + ((r * 128 + kt * 32 + ag * 8) ^ asw)];
    const bf16x8* b = (const bf16x8*)(MT_ws + (size_t)(r * 128 + n0) * 128 + ag * 8);
    f32x4 acc = {0.f, 0.f, 0.f, 0.f};
    #pragma unroll
    for (int kt = 0; kt < 4; ++kt)
      acc = __builtin_amdgcn_mfma_f32_16x16x32_bf16(a[kt], b[kt * 4], acc, 0, 0, 0);
    #pragma unroll
    for (int v = 0; v < 4; ++v) {
      int i = ag * 4 + v, isw = (i & 7) << 3;
      Ys[i * NN + ((r * 128 + n0) ^ isw)] = f2bf_hw(acc[v] + cv[r]);
    }
  }

  // ---- scatter T1 -> Xs1
  #pragma unroll
  for (int ch = 0; ch < 4; ++ch) {
    int4 p4 = p4c[ch];
    #pragma unroll
    for (int rl = 0; rl < 2; ++rl) {
      int row = w * 2 + rl;
      int base = row * NN, sw = (row & 7) << 3;
      float4 v = pv[ch][rl];
      Xs[1][base + (p4.x ^ sw)] = f2bf_hw(v.x);
      Xs[1][base + (p4.y ^ sw)] = f2bf_hw(v.y);
      Xs[1][base + (p4.z ^ sw)] = f2bf_hw(v.z);
      Xs[1][base + (p4.w ^ sw)] = f2bf_hw(v.w);
    }
  }
  __syncthreads();                                           // (2)

  // ---- compute T1 into acc regs (reads Xs1 + MT)  ||  gather+store T0 (reads Ys)
  f32x4 accr[NREG];
  #pragma unroll
  for (int r = 0; r < NREG; ++r) {
    bf16x8 a[4];
    #pragma unroll
    for (int kt = 0; kt < 4; ++kt)
      a[kt] = *(const bf16x8*)&Xs[1][arow * NN + ((r * 128 + kt * 32 + ag * 8) ^ asw)];
    const bf16x8* b = (const bf16x8*)(MT_ws + (size_t)(r * 128 + n0) * 128 + ag * 8);
    accr[r] = (f32x4){0.f, 0.f, 0.f, 0.f};
    #pragma unroll
    for (int kt = 0; kt < 4; ++kt)
      accr[r] = __builtin_amdgcn_mfma_f32_16x16x32_bf16(a[kt], b[kt * 4], accr[r], 0, 0, 0);
  }
  #pragma unroll
  for (int ch = 0; ch < 4; ++ch) {
    int j = ch * 256 + lane * 4;
    int4 p4 = p4c[ch];
    #pragma unroll
    for (int rl = 0; rl < 2; ++rl) {
      int row = w * 2 + rl;
      int base = row * NN, sw = (row & 7) << 3;
      float4 v;
      v.x = bf2f(Ys[base + (p4.x ^ sw)]);
      v.y = bf2f(Ys[base + (p4.y ^ sw)]);
      v.z = bf2f(Ys[base + (p4.z ^ sw)]);
      v.w = bf2f(Ys[base + (p4.w ^ sw)]);
      *(float4*)&out[(row0 + row) * NN + j] = v;
    }
  }
  __syncthreads();                                           // (3)

  // ---- write T1 results -> Ys
  #pragma unroll
  for (int r = 0; r < NREG; ++r)
    #pragma unroll
    for (int v = 0; v < 4; ++v) {
      int i = ag * 4 + v, isw = (i & 7) << 3;
      Ys[i * NN + ((r * 128 + n0) ^ isw)] = f2bf_hw(accr[r][v] + cv[r]);
    }
  __syncthreads();                                           // (4)

  // ---- gather+store T1
  #pragma unroll
  for (int ch = 0; ch < 4; ++ch) {
    int j = ch * 256 + lane * 4;
    int4 p4 = p4c[ch];
    #pragma unroll
    for (int rl = 0; rl < 2; ++rl) {
      int row = w * 2 + rl;
      int base = row * NN, sw = (row & 7) << 3;
      float4 v;
      v.x = bf2f(Ys[base + (p4.x ^ sw)]);
      v.y = bf2f(Ys[base + (p4.y ^ sw)]);
      v.z = bf2f(Ys[base + (p4.z ^ sw)]);
      v.w = bf2f(Ys[base + (p4.w ^ sw)]);
      *(float4*)&out[(row0 + ROWS + row) * NN + j] = v;
    }
  }
}

extern "C" void kernel_launch(void* const* d_in, const int* in_sizes, int n_in,
                              void* d_out, int out_size, void* d_ws, size_t ws_size,
                              hipStream_t stream) {
  const float* spikes = (const float*)d_in[0];
  const float* W_enc  = (const float*)d_in[1];
  const float* b_enc  = (const float*)d_in[2];
  const float* W_dec  = (const float*)d_in[3];
  const float* b_dec  = (const float*)d_in[4];
  const int*   idx    = (const int*)d_in[5];
  float* out = (float*)d_out;

  char* ws = (char*)d_ws;
  int*            pos_ws  = (int*)ws;
  float*          c_ws    = (float*)(ws + 4096);
  unsigned short* MT_ws   = (unsigned short*)(ws + 8192);
  float*          part    = (float*)(ws + 270336);
  float*          part_c  = (float*)(ws + 2367488);

  prep1_kernel<<<33, 256, 0, stream>>>(W_enc, b_enc, W_dec, idx,
                                       pos_ws, part, part_c);
  prep2_kernel<<<132, 256, 0, stream>>>(part, part_c, b_dec, MT_ws, c_ws);
  codec_kernel<<<8192 / (ROWS * SUBT), 512, 0, stream>>>(spikes, pos_ws, c_ws, MT_ws, out);
}

// Round 7
// 32.653 us; speedup vs baseline: 3.5000x; 1.2165x over previous
//
#include <hip/hip_runtime.h>
#include <hip/hip_bf16.h>

// RegionCodecDict: out[b,t,idx[r][n]] = sum_m spikes[b,t,idx[r][m]] * M[r][m][n] + c[r][n]
// where M[r] = W_enc[r] @ W_dec[r]  (128x128), c[r] = b_enc[r] @ W_dec[r] + b_dec[r]
// (the reference is purely linear between the two einsums, so they collapse).
//
// ws layout (~2.4 MB):
//   pos    : int[1024]               @ 0        inverse permutation
//   c      : float[8*128]            @ 4096
//   MTp    : ushort(bf16)[8*128*128] @ 8192     wave-tiled: chunk (r*32+w*4+kt)*64+(arow*4+ag)
//   part   : float[32*16384]         @ 270336   per-(r,dc) 128x128 f32 GEMM partials
//   part_c : float[32*8*128]         @ 2367488  per-(r,dc,dlb) c partials

typedef __attribute__((ext_vector_type(8))) short bf16x8;
typedef __attribute__((ext_vector_type(4))) float f32x4;
typedef __attribute__((ext_vector_type(4))) short s16x4;

#define NREG 8
#define NRD  128
#define DD   512
#define NN   1024
#define ROWS 16

static __device__ __forceinline__ unsigned short f2bf(float x) {
  union { float f; unsigned u; } v; v.f = x;
  unsigned r = v.u + 0x7fffu + ((v.u >> 16) & 1u);   // RNE
  return (unsigned short)(r >> 16);
}
static __device__ __forceinline__ unsigned short f2bf_hw(float x) {
  union { __hip_bfloat16 h; unsigned short u; } c;
  c.h = __float2bfloat16(x);
  return c.u;
}
static __device__ __forceinline__ float bf2f(unsigned short b) {
  union { unsigned u; float f; } v; v.u = ((unsigned)b) << 16;
  return v.f;
}

// ---------- prep1: 32 GEMM-partial blocks (r x d-chunk) + 1 pos block ----------
__global__ __launch_bounds__(256) void prep1_kernel(
    const float* __restrict__ W_enc, const float* __restrict__ b_enc,
    const float* __restrict__ W_dec, const int* __restrict__ idx,
    int* __restrict__ pos_ws, float* __restrict__ part,
    float* __restrict__ part_c)
{
  __shared__ unsigned short As[128 * 128];   // As[n][d^sw(n)]  (Wd^T slice)
  __shared__ unsigned short Bs[128 * 128];   // Bs[k][d^sw(k)]  (We slice)
  int blk = blockIdx.x, t = threadIdx.x;

  if (blk < 32) {
    int r = blk >> 2, dc = blk & 3, d0 = dc * 128;
    const float* We = W_enc + (size_t)r * NRD * DD;
    const float* Wd = W_dec + (size_t)r * DD * NRD;
    const float* be = b_enc + (size_t)r * DD;

    // stage As: transpose-scatter Wd[d0+dl][n] -> As[n][dl^sw]; fuse c partials
    int n4 = (t & 31) * 4, dlb = t >> 5;     // dlb in 0..7
    float c0 = 0.f, c1 = 0.f, c2 = 0.f, c3 = 0.f;
    #pragma unroll
    for (int p = 0; p < 16; ++p) {
      int dl = dlb + p * 8;
      float4 v = *(const float4*)&Wd[(size_t)(d0 + dl) * NRD + n4];
      float bev = be[d0 + dl];
      As[(n4 + 0) * 128 + (dl ^ (((n4 + 0) & 7) << 3))] = f2bf(v.x);
      As[(n4 + 1) * 128 + (dl ^ (((n4 + 1) & 7) << 3))] = f2bf(v.y);
      As[(n4 + 2) * 128 + (dl ^ (((n4 + 2) & 7) << 3))] = f2bf(v.z);
      As[(n4 + 3) * 128 + (dl ^ (((n4 + 3) & 7) << 3))] = f2bf(v.w);
      c0 += v.x * bev; c1 += v.y * bev; c2 += v.z * bev; c3 += v.w * bev;
    }
    {
      float4 cv; cv.x = c0; cv.y = c1; cv.z = c2; cv.w = c3;
      *(float4*)&part_c[((size_t)(r * 4 + dc) * 8 + dlb) * 128 + n4] = cv;
    }
    // stage Bs: straight copy We[k][d0..d0+128]
    #pragma unroll
    for (int i = 0; i < 8; ++i) {
      int cid = t + i * 256;
      int k = cid >> 4, dq = (cid & 15) * 8;
      const float* src = &We[(size_t)k * DD + d0 + dq];
      float4 u = *(const float4*)src;
      float4 u2 = *(const float4*)(src + 4);
      bf16x8 pk;
      pk[0] = (short)f2bf(u.x);  pk[1] = (short)f2bf(u.y);
      pk[2] = (short)f2bf(u.z);  pk[3] = (short)f2bf(u.w);
      pk[4] = (short)f2bf(u2.x); pk[5] = (short)f2bf(u2.y);
      pk[6] = (short)f2bf(u2.z); pk[7] = (short)f2bf(u2.w);
      *(bf16x8*)&Bs[k * 128 + (dq ^ ((k & 7) << 3))] = pk;
    }
    __syncthreads();

    int lane = t & 63, w = t >> 6;
    int arow = lane & 15, ag = lane >> 4;
    f32x4 acc[8][2];
    #pragma unroll
    for (int i = 0; i < 8; ++i) {
      acc[i][0] = (f32x4){0.f, 0.f, 0.f, 0.f};
      acc[i][1] = (f32x4){0.f, 0.f, 0.f, 0.f};
    }
    #pragma unroll
    for (int nt = 0; nt < 8; ++nt) {
      int nl = nt * 16 + arow, asw = (nl & 7) << 3;
      bf16x8 a[4];
      #pragma unroll
      for (int ks = 0; ks < 4; ++ks)
        a[ks] = *(const bf16x8*)&As[nl * 128 + ((ks * 32 + ag * 8) ^ asw)];
      #pragma unroll
      for (int kt = 0; kt < 2; ++kt) {
        int kk = w * 32 + kt * 16 + arow, bsw = (kk & 7) << 3;
        #pragma unroll
        for (int ks = 0; ks < 4; ++ks) {
          bf16x8 b = *(const bf16x8*)&Bs[kk * 128 + ((ks * 32 + ag * 8) ^ bsw)];
          acc[nt][kt] = __builtin_amdgcn_mfma_f32_16x16x32_bf16(a[ks], b, acc[nt][kt], 0, 0, 0);
        }
      }
    }
    float* dst = part + (size_t)(r * 4 + dc) * 16384;
    #pragma unroll
    for (int nt = 0; nt < 8; ++nt)
      #pragma unroll
      for (int kt = 0; kt < 2; ++kt)
        #pragma unroll
        for (int v = 0; v < 4; ++v)
          dst[(nt * 16 + ag * 4 + v) * 128 + (w * 32 + kt * 16 + arow)] = acc[nt][kt][v];
  } else {
    // pos block
    #pragma unroll
    for (int i = 0; i < 4; ++i) {
      int q = t * 4 + i;
      pos_ws[idx[q]] = q;
    }
  }
}

// ---------- prep2: reduce partials -> MTp (bf16, wave-tiled layout) and c (f32) ----------
// MTp element offset for (r, n, k):  n = w*16+arow, k = kt*32+ag*8+sub
//   chunk = (r*32 + w*4 + kt)*64 + (arow*4 + ag);  offset = chunk*8 + sub
// -> each codec B-load (fixed r,kt per wave) reads one contiguous 1KB tile.
__global__ __launch_bounds__(256) void prep2_kernel(
    const float* __restrict__ part, const float* __restrict__ part_c,
    const float* __restrict__ b_dec, unsigned short* __restrict__ MTp,
    float* __restrict__ c_ws)
{
  int blk = blockIdx.x, t = threadIdx.x;
  if (blk < 128) {
    int e0 = (blk * 256 + t) * 4;
    int r = e0 >> 14, off = e0 & 16383;
    int n = off >> 7, k0 = off & 127;
    const float* p = part + (size_t)r * 4 * 16384 + off;
    float4 s0 = *(const float4*)&p[0];
    float4 s1 = *(const float4*)&p[16384];
    float4 s2 = *(const float4*)&p[32768];
    float4 s3 = *(const float4*)&p[49152];
    s16x4 o;
    o.x = (short)f2bf(s0.x + s1.x + s2.x + s3.x);
    o.y = (short)f2bf(s0.y + s1.y + s2.y + s3.y);
    o.z = (short)f2bf(s0.z + s1.z + s2.z + s3.z);
    o.w = (short)f2bf(s0.w + s1.w + s2.w + s3.w);
    int w = n >> 4, arow = n & 15, kt = k0 >> 5, ag = (k0 >> 3) & 3, sub = k0 & 7;
    int chunk = (r * 32 + w * 4 + kt) * 64 + (arow * 4 + ag);
    *(s16x4*)&MTp[chunk * 8 + sub] = o;
  } else if (blk < 132) {
    int e = (blk - 128) * 256 + t;
    int n = e & 127;
    int r = e >> 7;
    float s = b_dec[e];
    #pragma unroll
    for (int dc = 0; dc < 4; ++dc)
      #pragma unroll
      for (int g = 0; g < 8; ++g)
        s += part_c[((size_t)(r * 4 + dc) * 8 + g) * 128 + n];
    c_ws[e] = s;
  }
}

// ---------- main codec ----------
// stage (permuted bf16 scatter) | B | per-region: coalesced B (dbuf) + LDS A + MFMA,
// scatter result by idx into OUTPUT-LINEAR Ys | B | vectorized b64 gather + f32 stores
__global__ __launch_bounds__(512) void codec_kernel(
    const float* __restrict__ spikes, const int* __restrict__ pos_ws,
    const float* __restrict__ c_ws, const unsigned short* __restrict__ MTp,
    const int* __restrict__ idx, float* __restrict__ out)
{
  __shared__ unsigned short Xs[ROWS * NN];   // region-permuted input, row-swizzled
  __shared__ unsigned short Ys[ROWS * NN];   // OUTPUT-LINEAR result, row-swizzled
  int t = threadIdx.x;
  int w = t >> 6, lane = t & 63;             // 8 waves
  int arow = lane & 15, ag = lane >> 4;
  int n0 = w * 16 + arow;                    // wave w owns region-cols [16w, 16w+16)
  int lanechunk = arow * 4 + ag;
  size_t row0 = (size_t)blockIdx.x * ROWS;

  // register-cached permutation, bias, output columns
  int4 p4c[4];
  #pragma unroll
  for (int ch = 0; ch < 4; ++ch)
    p4c[ch] = *(const int4*)&pos_ws[ch * 256 + lane * 4];
  float cv[NREG];
  int col[NREG];
  #pragma unroll
  for (int r = 0; r < NREG; ++r) {
    cv[r]  = c_ws[r * 128 + n0];
    col[r] = idx[r * 128 + n0];
  }

  // ---- stage: coalesced float4 reads (2 rows per wave), bf16 scatter into permuted LDS
  #pragma unroll
  for (int ch = 0; ch < 4; ++ch) {
    int j = ch * 256 + lane * 4;
    int4 p4 = p4c[ch];
    #pragma unroll
    for (int rl = 0; rl < 2; ++rl) {
      int row = w * 2 + rl;
      float4 v = *(const float4*)&spikes[(row0 + row) * NN + j];
      int base = row * NN, sw = (row & 7) << 3;
      Xs[base + (p4.x ^ sw)] = f2bf_hw(v.x);
      Xs[base + (p4.y ^ sw)] = f2bf_hw(v.y);
      Xs[base + (p4.z ^ sw)] = f2bf_hw(v.z);
      Xs[base + (p4.w ^ sw)] = f2bf_hw(v.w);
    }
  }
  __syncthreads();

  // ---- per region: coalesced 1KB B-tile loads (2-deep dbuf), A from LDS, MFMA
  const bf16x8* Bb = (const bf16x8*)MTp;     // chunk-indexed: (r*32 + w*4 + kt)*64 + lanechunk
  int asw = (arow & 7) << 3;
  bf16x8 bb[2][4];
  #pragma unroll
  for (int kt = 0; kt < 4; ++kt)
    bb[0][kt] = Bb[(w * 4 + kt) * 64 + lanechunk];
  #pragma unroll
  for (int r = 0; r < NREG; ++r) {
    if (r < NREG - 1) {
      #pragma unroll
      for (int kt = 0; kt < 4; ++kt)
        bb[(r + 1) & 1][kt] = Bb[((r + 1) * 32 + w * 4 + kt) * 64 + lanechunk];
    }
    bf16x8 a[4];
    #pragma unroll
    for (int kt = 0; kt < 4; ++kt)
      a[kt] = *(const bf16x8*)&Xs[arow * NN + ((r * 128 + kt * 32 + ag * 8) ^ asw)];
    f32x4 acc = {0.f, 0.f, 0.f, 0.f};
    #pragma unroll
    for (int kt = 0; kt < 4; ++kt)
      acc = __builtin_amdgcn_mfma_f32_16x16x32_bf16(a[kt], bb[r & 1][kt], acc, 0, 0, 0);
    #pragma unroll
    for (int v = 0; v < 4; ++v) {            // D[i][j]: i = 4*(lane/16)+v, j = lane%16
      int i = ag * 4 + v, isw = (i & 7) << 3;
      Ys[i * NN + (col[r] ^ isw)] = f2bf_hw(acc[v] + cv[r]);
    }
  }
  __syncthreads();

  // ---- writeback: vectorized b64 reads of output-linear Ys, coalesced f32x4 stores
  #pragma unroll
  for (int ch = 0; ch < 4; ++ch) {
    int j = ch * 256 + lane * 4;
    #pragma unroll
    for (int rl = 0; rl < 2; ++rl) {
      int row = w * 2 + rl;
      int sw = (row & 7) << 3;
      s16x4 y = *(const s16x4*)&Ys[row * NN + (j ^ sw)];
      float4 v;
      v.x = bf2f((unsigned short)y.x);
      v.y = bf2f((unsigned short)y.y);
      v.z = bf2f((unsigned short)y.z);
      v.w = bf2f((unsigned short)y.w);
      *(float4*)&out[(row0 + row) * NN + j] = v;
    }
  }
}

extern "C" void kernel_launch(void* const* d_in, const int* in_sizes, int n_in,
                              void* d_out, int out_size, void* d_ws, size_t ws_size,
                              hipStream_t stream) {
  const float* spikes = (const float*)d_in[0];
  const float* W_enc  = (const float*)d_in[1];
  const float* b_enc  = (const float*)d_in[2];
  const float* W_dec  = (const float*)d_in[3];
  const float* b_dec  = (const float*)d_in[4];
  const int*   idx    = (const int*)d_in[5];
  float* out = (float*)d_out;

  char* ws = (char*)d_ws;
  int*            pos_ws  = (int*)ws;
  float*          c_ws    = (float*)(ws + 4096);
  unsigned short* MTp_ws  = (unsigned short*)(ws + 8192);
  float*          part    = (float*)(ws + 270336);
  float*          part_c  = (float*)(ws + 2367488);

  prep1_kernel<<<33, 256, 0, stream>>>(W_enc, b_enc, W_dec, idx,
                                       pos_ws, part, part_c);
  prep2_kernel<<<132, 256, 0, stream>>>(part, part_c, b_dec, MTp_ws, c_ws);
  codec_kernel<<<8192 / ROWS, 512, 0, stream>>>(spikes, pos_ws, c_ws, MTp_ws, idx, out);
}

// Round 8
// 32.565 us; speedup vs baseline: 3.5094x; 1.0027x over previous
//
#include <hip/hip_runtime.h>
#include <hip/hip_bf16.h>

// RegionCodecDict: out[b,t,idx[r][n]] = sum_m spikes[b,t,idx[r][m]] * M[r][m][n] + c[r][n]
// where M[r] = W_enc[r] @ W_dec[r]  (128x128), c[r] = b_enc[r] @ W_dec[r] + b_dec[r]
// (the reference is purely linear between the two einsums, so they collapse).
//
// ws layout (~2.4 MB):
//   pos    : int[1024]               @ 0        inverse permutation
//   c      : float[8*128]            @ 4096
//   MTp    : ushort(bf16)[8*128*128] @ 8192     wave-tiled: chunk (r*32+wcol*4+kt)*64+(arow*4+ag)
//   part   : float[32*16384]         @ 270336   per-(r,dc) 128x128 f32 GEMM partials
//   part_c : float[32*8*128]         @ 2367488  per-(r,dc,dlb) c partials

typedef __attribute__((ext_vector_type(8))) short bf16x8;
typedef __attribute__((ext_vector_type(4))) float f32x4;
typedef __attribute__((ext_vector_type(4))) short s16x4;

#define NREG 8
#define NRD  128
#define DD   512
#define NN   1024
#define ROWS 16

static __device__ __forceinline__ unsigned short f2bf(float x) {
  union { float f; unsigned u; } v; v.f = x;
  unsigned r = v.u + 0x7fffu + ((v.u >> 16) & 1u);   // RNE
  return (unsigned short)(r >> 16);
}
static __device__ __forceinline__ unsigned short f2bf_hw(float x) {
  union { __hip_bfloat16 h; unsigned short u; } c;
  c.h = __float2bfloat16(x);
  return c.u;
}
static __device__ __forceinline__ float bf2f(unsigned short b) {
  union { unsigned u; float f; } v; v.u = ((unsigned)b) << 16;
  return v.f;
}

// ---------- prep1: 32 GEMM-partial blocks (r x d-chunk) + 1 pos block ----------
__global__ __launch_bounds__(256) void prep1_kernel(
    const float* __restrict__ W_enc, const float* __restrict__ b_enc,
    const float* __restrict__ W_dec, const int* __restrict__ idx,
    int* __restrict__ pos_ws, float* __restrict__ part,
    float* __restrict__ part_c)
{
  __shared__ unsigned short As[128 * 128];   // As[n][d^sw(n)]  (Wd^T slice)
  __shared__ unsigned short Bs[128 * 128];   // Bs[k][d^sw(k)]  (We slice)
  int blk = blockIdx.x, t = threadIdx.x;

  if (blk < 32) {
    int r = blk >> 2, dc = blk & 3, d0 = dc * 128;
    const float* We = W_enc + (size_t)r * NRD * DD;
    const float* Wd = W_dec + (size_t)r * DD * NRD;
    const float* be = b_enc + (size_t)r * DD;

    // stage As: transpose-scatter Wd[d0+dl][n] -> As[n][dl^sw]; fuse c partials
    int n4 = (t & 31) * 4, dlb = t >> 5;     // dlb in 0..7
    float c0 = 0.f, c1 = 0.f, c2 = 0.f, c3 = 0.f;
    #pragma unroll
    for (int p = 0; p < 16; ++p) {
      int dl = dlb + p * 8;
      float4 v = *(const float4*)&Wd[(size_t)(d0 + dl) * NRD + n4];
      float bev = be[d0 + dl];
      As[(n4 + 0) * 128 + (dl ^ (((n4 + 0) & 7) << 3))] = f2bf(v.x);
      As[(n4 + 1) * 128 + (dl ^ (((n4 + 1) & 7) << 3))] = f2bf(v.y);
      As[(n4 + 2) * 128 + (dl ^ (((n4 + 2) & 7) << 3))] = f2bf(v.z);
      As[(n4 + 3) * 128 + (dl ^ (((n4 + 3) & 7) << 3))] = f2bf(v.w);
      c0 += v.x * bev; c1 += v.y * bev; c2 += v.z * bev; c3 += v.w * bev;
    }
    {
      float4 cv; cv.x = c0; cv.y = c1; cv.z = c2; cv.w = c3;
      *(float4*)&part_c[((size_t)(r * 4 + dc) * 8 + dlb) * 128 + n4] = cv;
    }
    // stage Bs: straight copy We[k][d0..d0+128]
    #pragma unroll
    for (int i = 0; i < 8; ++i) {
      int cid = t + i * 256;
      int k = cid >> 4, dq = (cid & 15) * 8;
      const float* src = &We[(size_t)k * DD + d0 + dq];
      float4 u = *(const float4*)src;
      float4 u2 = *(const float4*)(src + 4);
      bf16x8 pk;
      pk[0] = (short)f2bf(u.x);  pk[1] = (short)f2bf(u.y);
      pk[2] = (short)f2bf(u.z);  pk[3] = (short)f2bf(u.w);
      pk[4] = (short)f2bf(u2.x); pk[5] = (short)f2bf(u2.y);
      pk[6] = (short)f2bf(u2.z); pk[7] = (short)f2bf(u2.w);
      *(bf16x8*)&Bs[k * 128 + (dq ^ ((k & 7) << 3))] = pk;
    }
    __syncthreads();

    int lane = t & 63, w = t >> 6;
    int arow = lane & 15, ag = lane >> 4;
    f32x4 acc[8][2];
    #pragma unroll
    for (int i = 0; i < 8; ++i) {
      acc[i][0] = (f32x4){0.f, 0.f, 0.f, 0.f};
      acc[i][1] = (f32x4){0.f, 0.f, 0.f, 0.f};
    }
    #pragma unroll
    for (int nt = 0; nt < 8; ++nt) {
      int nl = nt * 16 + arow, asw = (nl & 7) << 3;
      bf16x8 a[4];
      #pragma unroll
      for (int ks = 0; ks < 4; ++ks)
        a[ks] = *(const bf16x8*)&As[nl * 128 + ((ks * 32 + ag * 8) ^ asw)];
      #pragma unroll
      for (int kt = 0; kt < 2; ++kt) {
        int kk = w * 32 + kt * 16 + arow, bsw = (kk & 7) << 3;
        #pragma unroll
        for (int ks = 0; ks < 4; ++ks) {
          bf16x8 b = *(const bf16x8*)&Bs[kk * 128 + ((ks * 32 + ag * 8) ^ bsw)];
          acc[nt][kt] = __builtin_amdgcn_mfma_f32_16x16x32_bf16(a[ks], b, acc[nt][kt], 0, 0, 0);
        }
      }
    }
    float* dst = part + (size_t)(r * 4 + dc) * 16384;
    #pragma unroll
    for (int nt = 0; nt < 8; ++nt)
      #pragma unroll
      for (int kt = 0; kt < 2; ++kt)
        #pragma unroll
        for (int v = 0; v < 4; ++v)
          dst[(nt * 16 + ag * 4 + v) * 128 + (w * 32 + kt * 16 + arow)] = acc[nt][kt][v];
  } else {
    // pos block
    #pragma unroll
    for (int i = 0; i < 4; ++i) {
      int q = t * 4 + i;
      pos_ws[idx[q]] = q;
    }
  }
}

// ---------- prep2: reduce partials -> MTp (bf16, wave-tiled layout) and c (f32) ----------
// MTp element offset for (r, n, k):  n = wcol*16+arow, k = kt*32+ag*8+sub
//   chunk = (r*32 + wcol*4 + kt)*64 + (arow*4 + ag);  offset = chunk*8 + sub
// -> each codec B-load (fixed r,kt per wave) reads one contiguous 1KB tile.
__global__ __launch_bounds__(256) void prep2_kernel(
    const float* __restrict__ part, const float* __restrict__ part_c,
    const float* __restrict__ b_dec, unsigned short* __restrict__ MTp,
    float* __restrict__ c_ws)
{
  int blk = blockIdx.x, t = threadIdx.x;
  if (blk < 128) {
    int e0 = (blk * 256 + t) * 4;
    int r = e0 >> 14, off = e0 & 16383;
    int n = off >> 7, k0 = off & 127;
    const float* p = part + (size_t)r * 4 * 16384 + off;
    float4 s0 = *(const float4*)&p[0];
    float4 s1 = *(const float4*)&p[16384];
    float4 s2 = *(const float4*)&p[32768];
    float4 s3 = *(const float4*)&p[49152];
    s16x4 o;
    o.x = (short)f2bf(s0.x + s1.x + s2.x + s3.x);
    o.y = (short)f2bf(s0.y + s1.y + s2.y + s3.y);
    o.z = (short)f2bf(s0.z + s1.z + s2.z + s3.z);
    o.w = (short)f2bf(s0.w + s1.w + s2.w + s3.w);
    int w = n >> 4, arow = n & 15, kt = k0 >> 5, ag = (k0 >> 3) & 3, sub = k0 & 7;
    int chunk = (r * 32 + w * 4 + kt) * 64 + (arow * 4 + ag);
    *(s16x4*)&MTp[chunk * 8 + sub] = o;
  } else if (blk < 132) {
    int e = (blk - 128) * 256 + t;
    int n = e & 127;
    int r = e >> 7;
    float s = b_dec[e];
    #pragma unroll
    for (int dc = 0; dc < 4; ++dc)
      #pragma unroll
      for (int g = 0; g < 8; ++g)
        s += part_c[((size_t)(r * 4 + dc) * 8 + g) * 128 + n];
    c_ws[e] = s;
  }
}

// ---------- main codec: 1024 threads / 16 waves (max occupancy: 32 waves/CU) ----------
// wave w: stages row w; computes regions [4*(w>>3), +4) for cols [16*(w&7), +16);
// writes back row w. Two barriers total. Ys kept output-linear (vectorized gather).
__global__ __launch_bounds__(1024) void codec_kernel(
    const float* __restrict__ spikes, const int* __restrict__ pos_ws,
    const float* __restrict__ c_ws, const unsigned short* __restrict__ MTp,
    const int* __restrict__ idx, float* __restrict__ out)
{
  __shared__ unsigned short Xs[ROWS * NN];   // region-permuted input, row-swizzled
  __shared__ unsigned short Ys[ROWS * NN];   // OUTPUT-LINEAR result, row-swizzled
  int t = threadIdx.x;
  int w = t >> 6, lane = t & 63;             // 16 waves
  int wg = w >> 3, wcol = w & 7;             // region-group, col-group
  int arow = lane & 15, ag = lane >> 4;
  int n0 = wcol * 16 + arow;
  int lanechunk = arow * 4 + ag;
  size_t row0 = (size_t)blockIdx.x * ROWS;

  // register-cached permutation, bias, output columns (4 regions per wave)
  int4 p4c[4];
  #pragma unroll
  for (int ch = 0; ch < 4; ++ch)
    p4c[ch] = *(const int4*)&pos_ws[ch * 256 + lane * 4];
  float cv[4];
  int col[4];
  #pragma unroll
  for (int q = 0; q < 4; ++q) {
    int r = wg * 4 + q;
    cv[q]  = c_ws[r * 128 + n0];
    col[q] = idx[r * 128 + n0];
  }

  // ---- stage: wave w loads row w (4 coalesced float4 chunks), scatters permuted bf16
  {
    int base = w * NN, sw = (w & 7) << 3;
    #pragma unroll
    for (int ch = 0; ch < 4; ++ch) {
      int j = ch * 256 + lane * 4;
      float4 v = *(const float4*)&spikes[(row0 + w) * NN + j];
      int4 p4 = p4c[ch];
      Xs[base + (p4.x ^ sw)] = f2bf_hw(v.x);
      Xs[base + (p4.y ^ sw)] = f2bf_hw(v.y);
      Xs[base + (p4.z ^ sw)] = f2bf_hw(v.z);
      Xs[base + (p4.w ^ sw)] = f2bf_hw(v.w);
    }
  }
  __syncthreads();

  // ---- compute: 4 regions per wave; coalesced 1KB B tiles, swizzled A from LDS
  const bf16x8* Bb = (const bf16x8*)MTp;
  int asw = (arow & 7) << 3;
  #pragma unroll
  for (int q = 0; q < 4; ++q) {
    int r = wg * 4 + q;
    bf16x8 b[4], a[4];
    #pragma unroll
    for (int kt = 0; kt < 4; ++kt)
      b[kt] = Bb[(r * 32 + wcol * 4 + kt) * 64 + lanechunk];
    #pragma unroll
    for (int kt = 0; kt < 4; ++kt)
      a[kt] = *(const bf16x8*)&Xs[arow * NN + ((r * 128 + kt * 32 + ag * 8) ^ asw)];
    f32x4 acc = {0.f, 0.f, 0.f, 0.f};
    #pragma unroll
    for (int kt = 0; kt < 4; ++kt)
      acc = __builtin_amdgcn_mfma_f32_16x16x32_bf16(a[kt], b[kt], acc, 0, 0, 0);
    #pragma unroll
    for (int v = 0; v < 4; ++v) {            // D[i][j]: i = 4*(lane/16)+v, j = lane%16
      int i = ag * 4 + v, isw = (i & 7) << 3;
      Ys[i * NN + (col[q] ^ isw)] = f2bf_hw(acc[v] + cv[q]);
    }
  }
  __syncthreads();

  // ---- writeback: wave w reads row w of output-linear Ys (b64), coalesced f32x4 stores
  {
    int sw = (w & 7) << 3;
    #pragma unroll
    for (int ch = 0; ch < 4; ++ch) {
      int j = ch * 256 + lane * 4;
      s16x4 y = *(const s16x4*)&Ys[w * NN + (j ^ sw)];
      float4 v;
      v.x = bf2f((unsigned short)y.x);
      v.y = bf2f((unsigned short)y.y);
      v.z = bf2f((unsigned short)y.z);
      v.w = bf2f((unsigned short)y.w);
      *(float4*)&out[(row0 + w) * NN + j] = v;
    }
  }
}

extern "C" void kernel_launch(void* const* d_in, const int* in_sizes, int n_in,
                              void* d_out, int out_size, void* d_ws, size_t ws_size,
                              hipStream_t stream) {
  const float* spikes = (const float*)d_in[0];
  const float* W_enc  = (const float*)d_in[1];
  const float* b_enc  = (const float*)d_in[2];
  const float* W_dec  = (const float*)d_in[3];
  const float* b_dec  = (const float*)d_in[4];
  const int*   idx    = (const int*)d_in[5];
  float* out = (float*)d_out;

  char* ws = (char*)d_ws;
  int*            pos_ws  = (int*)ws;
  float*          c_ws    = (float*)(ws + 4096);
  unsigned short* MTp_ws  = (unsigned short*)(ws + 8192);
  float*          part    = (float*)(ws + 270336);
  float*          part_c  = (float*)(ws + 2367488);

  prep1_kernel<<<33, 256, 0, stream>>>(W_enc, b_enc, W_dec, idx,
                                       pos_ws, part, part_c);
  prep2_kernel<<<132, 256, 0, stream>>>(part, part_c, b_dec, MTp_ws, c_ws);
  codec_kernel<<<8192 / ROWS, 1024, 0, stream>>>(spikes, pos_ws, c_ws, MTp_ws, idx, out);
}